// Round 18
// baseline (74.373 us; speedup 1.0000x reference)
//
#include <hip/hip_runtime.h>
#include <hip/hip_fp16.h>
#include <math.h>
#include <stdint.h>

#define U 50
#define TT 100
#define BB 256
#define SPLIT 12   // pairs [0,12) -> kh=0 (+ x-part); pairs [12,25) -> kh=1

typedef _Float16 half2v __attribute__((ext_vector_type(2)));

__device__ __forceinline__ float dot2_acc(uint32_t h2, uint32_t w2, float c) {
#if __has_builtin(__builtin_amdgcn_fdot2)
    return __builtin_amdgcn_fdot2(__builtin_bit_cast(half2v, h2),
                                  __builtin_bit_cast(half2v, w2), c, false);
#else
    half2v a = __builtin_bit_cast(half2v, h2);
    half2v b = __builtin_bit_cast(half2v, w2);
    return fmaf((float)a.x, (float)b.x, fmaf((float)a.y, (float)b.y, c));
#endif
}

__device__ __forceinline__ float sigmoid_fast(float x) {
    return 1.0f / (1.0f + __expf(-x));   // saturates cleanly, no NaN
}
__device__ __forceinline__ float tanh_fast(float x) {
    float e = __expf(2.0f * x);
    return 1.0f - 2.0f / (e + 1.0f);     // saturates cleanly, no NaN
}
__device__ __forceinline__ float param_act(float x, float mn, float mx) {
    float scale = 0.5f * (mx - mn);
    return tanh_fast(x) * scale + mn + scale;
}

// lgkm-only barrier: no vmcnt drain in the loop (round-14 lesson).
#define BAR() do {                                            \
    asm volatile("s_waitcnt lgkmcnt(0)" ::: "memory");        \
    __builtin_amdgcn_s_barrier();                             \
    asm volatile("" ::: "memory");                            \
} while (0)

// EIGHT waves per batch element (2 waves/SIMD -> hardware latency hiding).
// Wave w = (gate g = w&3, k-half kh = w>>2); lane l owns unit l. Per lane:
// 12-13 dot2 and 13 weight dwords (residency-trivial). Each wave writes one
// b32 partial z; post-barrier every wave reads all 8 partials, sums pairs,
// and runs the nonlin + c/h chain redundantly (identical bits), so each wave
// sees its own h16 writes in order and reloads its own k-half of h with no
// second barrier. SoA conflict-free exchanges, dbuf zpart, zero VMEM in loop.
__global__ __launch_bounds__(512, 2) void encoder_kernel(
    const float* __restrict__ x,        // (B,T,4)
    const float* __restrict__ state,    // (B,T,4)
    const float* __restrict__ kernel,   // (4,200)
    const float* __restrict__ rec,      // (50,200)
    const float* __restrict__ bias,     // (200,)
    const float* __restrict__ w_dv, const float* __restrict__ b_dv,
    const float* __restrict__ w_dt, const float* __restrict__ b_dt,
    const float* __restrict__ w_mj, const float* __restrict__ b_mj,
    const float* __restrict__ w_ma, const float* __restrict__ b_ma,
    const float* __restrict__ w_mi, const float* __restrict__ b_mi,
    float* __restrict__ out)            // act_seq (B*T) then idm (B*5)
{
    const int b   = blockIdx.x;
    const int tid = threadIdx.x;
    const int w   = tid >> 6;           // wave 0..7
    const int g   = w & 3;              // gate (0=i,1=f,2=g,3=o)
    const int kh  = w >> 2;             // k-half
    const int l   = tid & 63;
    const int cl  = (l < U) ? l : (U - 1);

    __shared__ __align__(16) float4 xlds[TT];        // staged x(b,:,:)
    __shared__ __align__(16) _Float16 h16[64];       // h state (f16)
    __shared__ float zpart[2][8][64];                // dbuf partial z, SoA
    __shared__ float idm[8];

    // ---- per-lane weights: gate g, k-half kh, column cl (<=13 pairs) ----
    const int p0 = kh ? SPLIT : 0;
    const int np = kh ? (25 - SPLIT) : SPLIT;        // 13 or 12
    uint32_t wpk[13];
    #pragma unroll
    for (int j = 0; j < 13; ++j) {
        float r0 = 0.0f, r1 = 0.0f;
        if (j < np) {
            const int p = p0 + j;
            r0 = rec[(2 * p) * 200 + g * U + cl];
            r1 = rec[(2 * p + 1) * 200 + g * U + cl];
        }
        half2v pk; pk.x = (_Float16)r0; pk.y = (_Float16)r1;
        wpk[j] = __builtin_bit_cast(uint32_t, pk);
    }

    float kc[4];
    #pragma unroll
    for (int f = 0; f < 4; ++f) kc[f] = kernel[f * 200 + g * U + cl];
    float bz = bias[g * U + cl];

    // ---- stage x into LDS (zero VMEM in the loop), init h ----
    if (tid < TT) xlds[tid] = ((const float4*)(x + (size_t)b * TT * 4))[tid];
    if (tid < 64) h16[tid] = (_Float16)0.0f;
    __syncthreads();

    float cstate = 0.0f;
    uint32_t hv[13];
    #pragma unroll
    for (int j = 0; j < 13; ++j) hv[j] = 0u;   // h(0) = 0

    const uint4* __restrict__ hq = (const uint4*)h16;
    const uint32_t* __restrict__ hd = (const uint32_t*)h16;

    for (int t = 0; t < TT; ++t) {
        const int buf = t & 1;

        // partial z for (gate g, k-half kh)
        float p;
        if (kh == 0) {
            float4 x4 = xlds[t];                 // broadcast ds_read_b128
            p = fmaf(x4.x, kc[0], fmaf(x4.y, kc[1],
                fmaf(x4.z, kc[2], fmaf(x4.w, kc[3], bz))));
            float a0 = 0.f, a1 = 0.f;
            #pragma unroll
            for (int j = 0; j < 12; j += 2) {
                a0 = dot2_acc(hv[j],     wpk[j],     a0);
                a1 = dot2_acc(hv[j + 1], wpk[j + 1], a1);
            }
            p += a0 + a1;
        } else {
            float a0 = 0.f, a1 = 0.f;
            #pragma unroll
            for (int j = 0; j < 12; j += 2) {
                a0 = dot2_acc(hv[j],     wpk[j],     a0);
                a1 = dot2_acc(hv[j + 1], wpk[j + 1], a1);
            }
            a0 = dot2_acc(hv[12], wpk[12], a0);
            p = a0 + a1;
        }
        zpart[buf][w][l] = p;                    // stride-4B: conflict-free

        BAR();                                   // zpart(t) visible

        // sum halves, redundant nonlin + c/h on ALL waves (identical bits)
        float z0 = zpart[buf][0][l] + zpart[buf][4][l];
        float z1 = zpart[buf][1][l] + zpart[buf][5][l];
        float z2 = zpart[buf][2][l] + zpart[buf][6][l];
        float z3 = zpart[buf][3][l] + zpart[buf][7][l];
        float gi = sigmoid_fast(z0);
        float gf = sigmoid_fast(z1);
        float gg = tanh_fast(z2);
        float go = sigmoid_fast(z3);
        cstate = fmaf(gf, cstate, gi * gg);
        float hn = go * tanh_fast(cstate);
        if (l < U) h16[l] = (_Float16)hn;        // 8x same-value write: benign

        // reload own k-half of packed h(t+1) (own-wave order via lgkmcnt)
        if (kh == 0) {
            uint4 q0 = hq[0], q1 = hq[1], q2 = hq[2];   // dwords 0..11
            hv[0] = q0.x; hv[1] = q0.y; hv[2]  = q0.z; hv[3]  = q0.w;
            hv[4] = q1.x; hv[5] = q1.y; hv[6]  = q1.z; hv[7]  = q1.w;
            hv[8] = q2.x; hv[9] = q2.y; hv[10] = q2.z; hv[11] = q2.w;
        } else {
            uint4 q0 = hq[3], q1 = hq[4], q2 = hq[5];   // dwords 12..23
            hv[0] = q0.x; hv[1] = q0.y; hv[2]  = q0.z; hv[3]  = q0.w;
            hv[4] = q1.x; hv[5] = q1.y; hv[6]  = q1.z; hv[7]  = q1.w;
            hv[8] = q2.x; hv[9] = q2.y; hv[10] = q2.z; hv[11] = q2.w;
            hv[12] = hd[24];                            // dword 24
        }
        // next step writes zpart[buf^1] -- the other buffer: 1 barrier/step.
    }

    // ---- 5 output heads (threads 0..4; wave 0 wrote h16 itself) ----
    if (tid < 5) {
        const float* wv = (tid == 0) ? w_dv : (tid == 1) ? w_dt :
                          (tid == 2) ? w_mj : (tid == 3) ? w_ma : w_mi;
        const float* bv = (tid == 0) ? b_dv : (tid == 1) ? b_dt :
                          (tid == 2) ? b_mj : (tid == 3) ? b_ma : b_mi;
        float s = bv[0];
        #pragma unroll
        for (int j = 0; j < U; ++j) s = fmaf((float)h16[j], wv[j], s);
        float v;
        if (tid == 0)      v = param_act(s, 15.0f, 35.0f);
        else if (tid == 1) v = param_act(s, 0.5f, 3.0f);
        else if (tid == 2) v = fmaxf(s, 0.0f);
        else if (tid == 3) v = param_act(s, 0.5f, 3.0f);
        else               v = param_act(s, 0.5f, 4.0f);
        idm[tid] = v;
        out[BB * TT + b * 5 + tid] = v;
    }
    __syncthreads();

    // ---- IDM physics over T (threads 0..99, single pass) ----
    if (tid < TT) {
        const float desired_v    = idm[0];
        const float desired_tgap = idm[1];
        const float min_jamx     = idm[2];
        const float max_act      = idm[3];
        const float min_act      = idm[4];
        const float inv_tsab = 1.0f / (2.0f * sqrtf(max_act * min_act));
        const float inv_dv   = 1.0f / desired_v;
        float4 s4 = ((const float4*)(state + (size_t)b * TT * 4))[tid];
        float vel = s4.x, dv = s4.z, dx = s4.w;
        float dgap = fmaf(desired_tgap, vel, fmaf(vel * dv, inv_tsab, min_jamx));
        float r1 = vel * inv_dv;
        r1 = r1 * r1; r1 = r1 * r1;   // ^4
        float r2 = dgap / dx;
        r2 = r2 * r2;                 // ^2
        out[b * TT + tid] = max_act * (1.0f - (r1 + r2));
    }
}

extern "C" void kernel_launch(void* const* d_in, const int* in_sizes, int n_in,
                              void* d_out, int out_size, void* d_ws, size_t ws_size,
                              hipStream_t stream) {
    const float* x      = (const float*)d_in[0];
    const float* state  = (const float*)d_in[1];
    const float* kern   = (const float*)d_in[2];
    const float* rec    = (const float*)d_in[3];
    const float* bias   = (const float*)d_in[4];
    const float* w_dv   = (const float*)d_in[5];
    const float* b_dv   = (const float*)d_in[6];
    const float* w_dt   = (const float*)d_in[7];
    const float* b_dt   = (const float*)d_in[8];
    const float* w_mj   = (const float*)d_in[9];
    const float* b_mj   = (const float*)d_in[10];
    const float* w_ma   = (const float*)d_in[11];
    const float* b_ma   = (const float*)d_in[12];
    const float* w_mi   = (const float*)d_in[13];
    const float* b_mi   = (const float*)d_in[14];
    float* out = (float*)d_out;

    encoder_kernel<<<BB, 512, 0, stream>>>(
        x, state, kern, rec, bias,
        w_dv, b_dv, w_dt, b_dt, w_mj, b_mj, w_ma, b_ma, w_mi, b_mi,
        out);
}

// Round 19
// 51.043 us; speedup vs baseline: 1.4571x; 1.4571x over previous
//
#include <hip/hip_runtime.h>
#include <hip/hip_fp16.h>
#include <math.h>
#include <stdint.h>

#define U 50
#define TT 100
#define BB 256

typedef _Float16 f16x8 __attribute__((ext_vector_type(8)));
typedef float    f32x4 __attribute__((ext_vector_type(4)));

__device__ __forceinline__ float sigmoid_fast(float x) {
    return 1.0f / (1.0f + __expf(-x));   // saturates cleanly, no NaN
}
__device__ __forceinline__ float tanh_fast(float x) {
    float e = __expf(2.0f * x);
    return 1.0f - 2.0f / (e + 1.0f);     // saturates cleanly, no NaN
}
__device__ __forceinline__ float param_act(float x, float mn, float mx) {
    float scale = 0.5f * (mx - mn);
    return tanh_fast(x) * scale + mn + scale;
}

// lgkm-only barrier: no vmcnt drain in the loop (round-14 lesson).
#define BAR() do {                                            \
    asm volatile("s_waitcnt lgkmcnt(0)" ::: "memory");        \
    __builtin_amdgcn_s_barrier();                             \
    asm volatile("" ::: "memory");                            \
} while (0)

// 4 waves per batch; wave w = gate w. z_w(1x64) = h~(1x64) @ W~_w(64x64) via
// 8 MFMA intrinsics (4 independent 2-chains). B-fragments stay in AGPR/VGPR
// and are read by the matrix pipe for FREE -- ends the weight-residency war
// (rounds 2-17: any VALU-consumed weight path cost ~100 restores/step).
// K=64 = [h(50) | x(4) | 1 | 0..]: x-part and bias folded into the matmul
// (f16 x proven safe in round 16, layout proven correct in round 10).
// One lgkm-only barrier per step; h~ single-buffered (all A-reads precede
// the barrier, all h-writes follow it); zex double-buffered SoA.
__global__ __launch_bounds__(256, 1) void encoder_kernel(
    const float* __restrict__ x,        // (B,T,4)
    const float* __restrict__ state,    // (B,T,4)
    const float* __restrict__ kernel,   // (4,200)
    const float* __restrict__ rec,      // (50,200)
    const float* __restrict__ bias,     // (200,)
    const float* __restrict__ w_dv, const float* __restrict__ b_dv,
    const float* __restrict__ w_dt, const float* __restrict__ b_dt,
    const float* __restrict__ w_mj, const float* __restrict__ b_mj,
    const float* __restrict__ w_ma, const float* __restrict__ b_ma,
    const float* __restrict__ w_mi, const float* __restrict__ b_mi,
    float* __restrict__ out)            // act_seq (B*T) then idm (B*5)
{
    const int b   = blockIdx.x;
    const int tid = threadIdx.x;
    const int w   = tid >> 6;           // gate (0=i,1=f,2=g,3=o)
    const int l   = tid & 63;
    const int c   = l & 15;
    const int q   = l >> 4;

    __shared__ __align__(16) float4 xlds[TT];        // staged x(b,:,:)
    __shared__ __align__(16) _Float16 hbb[64];       // h~ = [h|x|1|0]
    __shared__ float zex[2][4][64];                  // dbuf SoA nonlinearities
    __shared__ float idm[8];

    // ---- stage W~ fragments for THIS gate (8 frags; layout proven in R10):
    // frag[nt][ks] elem e = W~[k = 32*ks + 8*q + e][col = 16*nt + c]
    f16x8 wf[4][2];
    #pragma unroll
    for (int nt = 0; nt < 4; ++nt) {
        const int uu = 16 * nt + c;
        #pragma unroll
        for (int ks = 0; ks < 2; ++ks) {
            f16x8 f;
            #pragma unroll
            for (int e = 0; e < 8; ++e) {
                const int j = 32 * ks + 8 * q + e;
                float v = 0.0f;
                if (uu < U) {
                    if (j < U)           v = rec[j * 200 + w * U + uu];
                    else if (j < U + 4)  v = kernel[(j - U) * 200 + w * U + uu];
                    else if (j == U + 4) v = bias[w * U + uu];
                }
                f[e] = (_Float16)v;
            }
            wf[nt][ks] = f;
        }
    }

    // ---- stage x into LDS; init h~(0) = [0 | x(0) | 1 | 0] ----
    if (tid < TT) xlds[tid] = ((const float4*)(x + (size_t)b * TT * 4))[tid];
    if (tid < 64) {
        _Float16 v = (_Float16)0.0f;
        if (tid >= U && tid < U + 4) v = (_Float16)x[(size_t)b * TT * 4 + (tid - U)];
        if (tid == U + 4) v = (_Float16)1.0f;
        hbb[tid] = v;
    }
    __syncthreads();

    float cstate = 0.0f;
    const uint4* __restrict__ hq = (const uint4*)hbb;
    const float* __restrict__ xf = (const float*)xlds;
    const f32x4 zero4 = {0.f, 0.f, 0.f, 0.f};

    for (int t = 0; t < TT; ++t) {
        const int buf = t & 1;

        // A-operand: 2 broadcast ds_read_b128 (elem e = h~[32*ks + 8q + e])
        uint4 a0u = hq[q];
        uint4 a1u = hq[4 + q];
        f16x8 A0 = __builtin_bit_cast(f16x8, a0u);
        f16x8 A1 = __builtin_bit_cast(f16x8, a1u);

        // x(t+1) for the h~ refill (lanes 50..53), issued early
        float xnext = 0.0f;
        if (l >= U && l < U + 4)
            xnext = xf[((t + 1 < TT) ? (t + 1) : t) * 4 + (l - U)];

        // 8 MFMA: 4 independent 2-chains (intrinsic -> hazards managed)
        f32x4 a0 = __builtin_amdgcn_mfma_f32_16x16x32_f16(A0, wf[0][0], zero4, 0, 0, 0);
        f32x4 a1 = __builtin_amdgcn_mfma_f32_16x16x32_f16(A0, wf[1][0], zero4, 0, 0, 0);
        f32x4 a2 = __builtin_amdgcn_mfma_f32_16x16x32_f16(A0, wf[2][0], zero4, 0, 0, 0);
        f32x4 a3 = __builtin_amdgcn_mfma_f32_16x16x32_f16(A0, wf[3][0], zero4, 0, 0, 0);
        a0 = __builtin_amdgcn_mfma_f32_16x16x32_f16(A1, wf[0][1], a0, 0, 0, 0);
        a1 = __builtin_amdgcn_mfma_f32_16x16x32_f16(A1, wf[1][1], a1, 0, 0, 0);
        a2 = __builtin_amdgcn_mfma_f32_16x16x32_f16(A1, wf[2][1], a2, 0, 0, 0);
        a3 = __builtin_amdgcn_mfma_f32_16x16x32_f16(A1, wf[3][1], a3, 0, 0, 0);

        // lane (c,q) owns unit l = 16q+c -> tile nt=q, col c, any row (reg 0)
        float z = (q == 0) ? a0[0] : (q == 1) ? a1[0] : (q == 2) ? a2[0] : a3[0];

        // own gate's nonlinearity (4 exps in parallel across waves)
        float nl = (w == 2) ? tanh_fast(z) : sigmoid_fast(z);
        zex[buf][w][l] = nl;                 // stride-4B: conflict-free

        BAR();                               // zex(t) visible

        // redundant c/h on ALL waves (identical bits)
        float gi = zex[buf][0][l];
        float gf = zex[buf][1][l];
        float gg = zex[buf][2][l];
        float go = zex[buf][3][l];
        cstate = fmaf(gf, cstate, gi * gg);
        float hn = go * tanh_fast(cstate);
        if (l < U)              hbb[l] = (_Float16)hn;     // 4x same-value: benign
        else if (l < U + 4)     hbb[l] = (_Float16)xnext;  // x(t+1)
        // hbb[54] stays 1.0; hbb[55..63] stay 0.
        // All A-reads of h~(t) happened pre-barrier; writes are post-barrier:
        // single h~ buffer is race-free. Own-wave write->read order covers
        // next iteration's A-read (lgkmcnt).
    }

    // ---- 5 output heads (threads 0..4; wave 0 wrote hbb itself) ----
    if (tid < 5) {
        const float* wv = (tid == 0) ? w_dv : (tid == 1) ? w_dt :
                          (tid == 2) ? w_mj : (tid == 3) ? w_ma : w_mi;
        const float* bv = (tid == 0) ? b_dv : (tid == 1) ? b_dt :
                          (tid == 2) ? b_mj : (tid == 3) ? b_ma : b_mi;
        float s = bv[0];
        #pragma unroll
        for (int j = 0; j < U; ++j) s = fmaf((float)hbb[j], wv[j], s);
        float v;
        if (tid == 0)      v = param_act(s, 15.0f, 35.0f);
        else if (tid == 1) v = param_act(s, 0.5f, 3.0f);
        else if (tid == 2) v = fmaxf(s, 0.0f);
        else if (tid == 3) v = param_act(s, 0.5f, 3.0f);
        else               v = param_act(s, 0.5f, 4.0f);
        idm[tid] = v;
        out[BB * TT + b * 5 + tid] = v;
    }
    __syncthreads();

    // ---- IDM physics over T (threads 0..99, single pass) ----
    if (tid < TT) {
        const float desired_v    = idm[0];
        const float desired_tgap = idm[1];
        const float min_jamx     = idm[2];
        const float max_act      = idm[3];
        const float min_act      = idm[4];
        const float inv_tsab = 1.0f / (2.0f * sqrtf(max_act * min_act));
        const float inv_dv   = 1.0f / desired_v;
        float4 s4 = ((const float4*)(state + (size_t)b * TT * 4))[tid];
        float vel = s4.x, dv = s4.z, dx = s4.w;
        float dgap = fmaf(desired_tgap, vel, fmaf(vel * dv, inv_tsab, min_jamx));
        float r1 = vel * inv_dv;
        r1 = r1 * r1; r1 = r1 * r1;   // ^4
        float r2 = dgap / dx;
        r2 = r2 * r2;                 // ^2
        out[b * TT + tid] = max_act * (1.0f - (r1 + r2));
    }
}

extern "C" void kernel_launch(void* const* d_in, const int* in_sizes, int n_in,
                              void* d_out, int out_size, void* d_ws, size_t ws_size,
                              hipStream_t stream) {
    const float* x      = (const float*)d_in[0];
    const float* state  = (const float*)d_in[1];
    const float* kern   = (const float*)d_in[2];
    const float* rec    = (const float*)d_in[3];
    const float* bias   = (const float*)d_in[4];
    const float* w_dv   = (const float*)d_in[5];
    const float* b_dv   = (const float*)d_in[6];
    const float* w_dt   = (const float*)d_in[7];
    const float* b_dt   = (const float*)d_in[8];
    const float* w_mj   = (const float*)d_in[9];
    const float* b_mj   = (const float*)d_in[10];
    const float* w_ma   = (const float*)d_in[11];
    const float* b_ma   = (const float*)d_in[12];
    const float* w_mi   = (const float*)d_in[13];
    const float* b_mi   = (const float*)d_in[14];
    float* out = (float*)d_out;

    encoder_kernel<<<BB, 256, 0, stream>>>(
        x, state, kern, rec, bias,
        w_dv, b_dv, w_dt, b_dt, w_mj, b_mj, w_ma, b_ma, w_mi, b_mi,
        out);
}